// Round 17
// baseline (6563.215 us; speedup 1.0000x reference)
//
#include <hip/hip_runtime.h>
#include <math.h>

namespace {

constexpr int kB = 512;
constexpr int kL = 128;
constexpr int kD = 128;
constexpr int kSteps = 126;   // L - 2
constexpr float kK = 2.8853900817779268f;  // 2*log2(e): exp(2y) = exp2(K*y)

// ---- workspace layout (float offsets) ----
constexpr size_t OFF_WL   = 0;          // [256][512] k-major: k<128 w_ih, else w_hh
constexpr size_t OFF_BIAS = 131072;     // [512] b_ih + b_hh
constexpr size_t OFF_WQLG = 131584;     // [16][256][4] lane-matched K*wq_g (P3)
constexpr size_t OFF_WQTP = 147968;     // [128][128] wq_p k-major (for encq prep)
constexpr size_t OFF_WRTG = 164352;     // [128][128] wr_g k-major
constexpr size_t OFF_WRTP = 180736;     // [128][128] wr_p k-major
constexpr size_t OFF_WIHT = 197120;     // [128][512] w_ih k-major (prep_gx)
constexpr size_t OFF_REFG = 262656;                                 // [L][B][D], K-scaled
constexpr size_t OFF_REFP = OFF_REFG + (size_t)kL * kB * kD;        // K-scaled
constexpr size_t OFF_ENCQ = OFF_REFP + (size_t)kL * kB * kD;        // K*(enc@wq_p^T+bq_p)
constexpr size_t kTotalNoGx = OFF_ENCQ + (size_t)kL * kB * kD;
constexpr size_t OFF_GX   = kTotalNoGx;                             // [129*512][512]
constexpr size_t kTotalGx = OFF_GX + (size_t)129 * kB * 512;        // ~237 MB

constexpr size_t OUT_IDX_OFF = (size_t)kSteps * kB * kL;  // probs first, then idx

// ---- dynamic LDS layout for decode_main (float offsets), ~73 KB ----
constexpr int SM_REFP = 0;      // [8 it][2 slot][256 t][4] = 16384 floats, conflict-free
constexpr int SM_H    = 16384;  // [128]
constexpr int SM_C    = 16512;  // [128]
constexpr int SM_G    = 16640;  // [512] gates
constexpr int SM_RED  = 17152;  // [256] P6 q_p partials (also x-staging in non-GX tier)
constexpr int SM_QG   = 17408;  // [128]
constexpr int SM_U    = 17536;  // [128]
constexpr int SM_PG   = 17664;  // [128] glimpse probs
constexpr int SM_M    = 17792;  // [128] mask
constexpr int SM_VG   = 17920;  // [128] holds 2*v_g
constexpr int SM_VP   = 18048;  // [128] holds 2*v_p
constexpr int SM_IDX  = 18176;  // int
constexpr int SM_TOTAL= 18180;

// fast transcendentals
__device__ __forceinline__ float tanh_fast(float x) {
  return 1.0f - __fdividef(2.0f, __expf(2.0f * x) + 1.0f);
}
__device__ __forceinline__ float sig_fast(float x) {
  return __fdividef(1.0f, 1.0f + __expf(-x));
}
// raw single-instruction transcendentals (guaranteed lowering)
__device__ __forceinline__ float exp2_raw(float x) {
  float r; asm("v_exp_f32 %0, %1" : "=v"(r) : "v"(x)); return r;
}
__device__ __forceinline__ float rcp_raw(float x) {
  float r; asm("v_rcp_f32 %0, %1" : "=v"(r) : "v"(x)); return r;
}

// anchor values in VGPRs at this program point (rule #17/#18)
#define KEEP4(v) asm volatile("" : "+v"(v.x), "+v"(v.y), "+v"(v.z), "+v"(v.w))
#define KEEP1(v) asm volatile("" : "+v"(v))

} // namespace

// ---------- one-time: weight relayouts + fused bias ----------
extern "C" __global__ void prep_weights(
    const float* __restrict__ w_ih, const float* __restrict__ w_hh,
    const float* __restrict__ b_ih, const float* __restrict__ b_hh,
    const float* __restrict__ wq_p, const float* __restrict__ wq_g,
    const float* __restrict__ wr_p, const float* __restrict__ wr_g,
    float* __restrict__ ws) {
  const int tid = blockIdx.x * blockDim.x + threadIdx.x;
  const int nth = gridDim.x * blockDim.x;
  for (int i = tid; i < 256 * 512; i += nth) {
    const int k = i >> 9, g = i & 511;
    ws[OFF_WL + i] = (k < 128) ? w_ih[g * 128 + k] : w_hh[g * 128 + (k - 128)];
  }
  for (int i = tid; i < 512; i += nth) ws[OFF_BIAS + i] = b_ih[i] + b_hh[i];
  // WQLG: K-scaled so P3 produces q_g' = K*q_g directly
  for (int i = tid; i < 16384; i += nth) {
    const int e = i & 3, rest = i >> 2;
    const int kq = rest & 1, j = (rest >> 1) & 127, kk4 = rest >> 8;
    const int k = kq * 64 + kk4 * 4 + e;
    ws[OFF_WQLG + i] = kK * wq_g[j * 128 + k];
  }
  for (int i = tid; i < 128 * 512; i += nth) {
    const int k = i >> 9, g = i & 511;
    ws[OFF_WIHT + i] = w_ih[g * 128 + k];
  }
  for (int i = tid; i < 128 * 128; i += nth) {
    const int k = i >> 7, j = i & 127;
    ws[OFF_WQTP + i] = wq_p[j * 128 + k];
    ws[OFF_WRTG + i] = wr_g[j * 128 + k];
    ws[OFF_WRTP + i] = wr_p[j * 128 + k];
  }
}

// ---------- one-time tiled GEMM: {ref_g, ref_p, encq} = K*(enc @ W + bias) ----------
extern "C" __global__ __launch_bounds__(256) void prep_mm(
    const float* __restrict__ enc,
    const float* __restrict__ br_g, const float* __restrict__ br_p,
    const float* __restrict__ bq_p,
    float* __restrict__ ws) {
  extern __shared__ float lds[];
  float* wT = lds;          // [128 k][128 j]
  float* sx = lds + 16384;  // [64 r][128 k]
  const int t = threadIdx.x;
  const int table = blockIdx.y;
  const size_t wOff = (table == 0) ? OFF_WRTG : (table == 1) ? OFF_WRTP : OFF_WQTP;
  const size_t oOff = (table == 0) ? OFF_REFG : (table == 1) ? OFF_REFP : OFF_ENCQ;
  const float* bias = (table == 0) ? br_g : (table == 1) ? br_p : bq_p;
  for (int i = t; i < 16384; i += 256) wT[i] = ws[wOff + i];
  const size_t r0 = (size_t)blockIdx.x * 64;   // rid = l*512 + b
  for (int i = t; i < 8192; i += 256) sx[i] = enc[r0 * 128 + i];
  __syncthreads();
  const int j0 = (t & 31) * 4, rg = t >> 5;
  float4 acc[8];
  const float4 b4 = *(const float4*)(bias + j0);
  #pragma unroll
  for (int r = 0; r < 8; ++r) acc[r] = b4;
  for (int k4 = 0; k4 < 32; ++k4) {
    const float4 w0 = *(const float4*)&wT[(k4 * 4 + 0) * 128 + j0];
    const float4 w1 = *(const float4*)&wT[(k4 * 4 + 1) * 128 + j0];
    const float4 w2 = *(const float4*)&wT[(k4 * 4 + 2) * 128 + j0];
    const float4 w3 = *(const float4*)&wT[(k4 * 4 + 3) * 128 + j0];
    #pragma unroll
    for (int r = 0; r < 8; ++r) {
      const float4 xv = *(const float4*)&sx[(rg * 8 + r) * 128 + k4 * 4];
      acc[r].x += xv.x * w0.x + xv.y * w1.x + xv.z * w2.x + xv.w * w3.x;
      acc[r].y += xv.x * w0.y + xv.y * w1.y + xv.z * w2.y + xv.w * w3.y;
      acc[r].z += xv.x * w0.z + xv.y * w1.z + xv.z * w2.z + xv.w * w3.z;
      acc[r].w += xv.x * w0.w + xv.y * w1.w + xv.z * w2.w + xv.w * w3.w;
    }
  }
  #pragma unroll
  for (int r = 0; r < 8; ++r) {
    acc[r].x *= kK; acc[r].y *= kK; acc[r].z *= kK; acc[r].w *= kK;
    *(float4*)&ws[oOff + (r0 + rg * 8 + r) * 128 + j0] = acc[r];
  }
}

// ---------- one-time tiled GEMM: gx[rid][g] = x_rid . w_ih[g,:] + bias[g] ----------
extern "C" __global__ __launch_bounds__(256) void prep_gx(
    const float* __restrict__ emb, const float* __restrict__ dec0,
    float* __restrict__ ws) {
  extern __shared__ float lds[];
  float* wT = lds;          // [128 k][128 g]
  float* sx = lds + 16384;  // [64 r][128 k]
  const int t = threadIdx.x;
  const int g0 = blockIdx.y * 128;
  for (int i = t; i < 16384; i += 256) {
    wT[i] = ws[OFF_WIHT + (size_t)(i >> 7) * 512 + g0 + (i & 127)];
  }
  const size_t r0 = (size_t)blockIdx.x * 64;
  for (int i = t; i < 8192; i += 256) {
    const size_t rid = r0 + (i >> 7);
    const int c = i & 127;
    sx[i] = (rid < 65536) ? emb[rid * 128 + c] : dec0[(rid - 65536) * 128 + c];
  }
  __syncthreads();
  const int j0 = (t & 31) * 4, rg = t >> 5;
  float4 acc[8];
  const float4 b4 = *(const float4*)(ws + OFF_BIAS + g0 + j0);
  #pragma unroll
  for (int r = 0; r < 8; ++r) acc[r] = b4;
  for (int k4 = 0; k4 < 32; ++k4) {
    const float4 w0 = *(const float4*)&wT[(k4 * 4 + 0) * 128 + j0];
    const float4 w1 = *(const float4*)&wT[(k4 * 4 + 1) * 128 + j0];
    const float4 w2 = *(const float4*)&wT[(k4 * 4 + 2) * 128 + j0];
    const float4 w3 = *(const float4*)&wT[(k4 * 4 + 3) * 128 + j0];
    #pragma unroll
    for (int r = 0; r < 8; ++r) {
      const float4 xv = *(const float4*)&sx[(rg * 8 + r) * 128 + k4 * 4];
      acc[r].x += xv.x * w0.x + xv.y * w1.x + xv.z * w2.x + xv.w * w3.x;
      acc[r].y += xv.x * w0.y + xv.y * w1.y + xv.z * w2.y + xv.w * w3.y;
      acc[r].z += xv.x * w0.z + xv.y * w1.z + xv.z * w2.z + xv.w * w3.z;
      acc[r].w += xv.x * w0.w + xv.y * w1.w + xv.z * w2.w + xv.w * w3.w;
    }
  }
  #pragma unroll
  for (int r = 0; r < 8; ++r) {
    *(float4*)&ws[OFF_GX + (r0 + rg * 8 + r) * 512 + g0 + j0] = acc[r];
  }
}

// ---------- persistent decode: one block per batch element, 256 threads, 2/CU ----------
// r16 + ENCQ prefetch issued at END of P4 (refg regs die there -> live ranges tile,
// peak pressure ~109 < 128; r15's step-top version stacked them -> spill).
template <bool GX>
__global__ __launch_bounds__(256, 2) void decode_main(
    const float* __restrict__ dec0, const float* __restrict__ emb,
    const float* __restrict__ h0,   const float* __restrict__ c0,
    const float* __restrict__ bq_g, const float* __restrict__ v_p,
    const float* __restrict__ v_g,
    const float* __restrict__ ws, float* __restrict__ out) {
  extern __shared__ float sm[];
  int* s_idx = (int*)(sm + SM_IDX);

  const int t = threadIdx.x;
  const int b = blockIdx.x;
  const int wv = t >> 6, lane = t & 63;
  const int sub = lane & 15, rr = lane >> 4;
  const int j2 = t >> 1, kq = t & 1;     // P3 mapping
  const int lh = t >> 7, dd = t & 127;   // P6 mapping

  // ---- startup: ref_p (K-scaled) -> LDS, conflict-free split-float4 slots ----
  #pragma unroll
  for (int it = 0; it < 8; ++it) {
    const int l = it * 16 + wv * 4 + rr;
    const float* src = ws + OFF_REFP + ((size_t)l * kB + b) * kD + sub * 8;
    *(float4*)&sm[SM_REFP + (it * 512 + t) * 4]       = *(const float4*)src;
    *(float4*)&sm[SM_REFP + (it * 512 + 256 + t) * 4] = *(const float4*)(src + 4);
  }
  if (t < 128) {
    sm[SM_H + t]  = h0[b * 128 + t];
    sm[SM_C + t]  = c0[b * 128 + t];
    sm[SM_M + t]  = (t < 2) ? 1.f : 0.f;   // indices 0,1 pre-visited
    sm[SM_VG + t] = 2.0f * v_g[t];         // 2v tables for the rcp form
    sm[SM_VP + t] = 2.0f * v_p[t];
  }
  if (t == 0) *s_idx = 128;   // sentinel: dec0 row
  const float bqg = kK * bq_g[j2];
  const float bias0 = ws[OFF_BIAS + 2 * t];
  const float bias1 = ws[OFF_BIAS + 2 * t + 1];
  __syncthreads();

  // vsum scalars (Σv = 0.5 * Σ(2v); broadcast LDS reads)
  float vgsum = 0.f, vpsum = 0.f;
  #pragma unroll 8
  for (int i = 0; i < 128; i += 4) {
    const float4 a = *(const float4*)&sm[SM_VG + i];
    const float4 p = *(const float4*)&sm[SM_VP + i];
    vgsum += a.x + a.y + a.z + a.w;
    vpsum += p.x + p.y + p.z + p.w;
  }
  vgsum *= 0.5f; vpsum *= 0.5f;

  const float* WL  = ws + OFF_WL;
  const float* WHH = WL + 128 * 512;
  const float* WQG = ws + OFF_WQLG + 4 * t;
  const float* REFG = ws + OFF_REFG;
  const float* GXT  = ws + OFF_GX;

  // per-it refg source pointers (step-invariant addresses)
  const float* rgp0 = REFG + ((size_t)( 0 + wv * 4 + rr) * kB + b) * kD + sub * 8;
  const float* rgp1 = REFG + ((size_t)(16 + wv * 4 + rr) * kB + b) * kD + sub * 8;
  const float* rgp2 = REFG + ((size_t)(32 + wv * 4 + rr) * kB + b) * kD + sub * 8;
  const float* rgp3 = REFG + ((size_t)(48 + wv * 4 + rr) * kB + b) * kD + sub * 8;
  const float* rgp4 = REFG + ((size_t)(64 + wv * 4 + rr) * kB + b) * kD + sub * 8;
  const float* rgp5 = REFG + ((size_t)(80 + wv * 4 + rr) * kB + b) * kD + sub * 8;
  const float* rgp6 = REFG + ((size_t)(96 + wv * 4 + rr) * kB + b) * kD + sub * 8;
  const float* rgp7 = REFG + ((size_t)(112 + wv * 4 + rr) * kB + b) * kD + sub * 8;
  // ENCQ source base (step-invariant): eqp[ll * kB*kD] = ENCQ[(lh*64+ll)*kB + b][dd]
  const float* eqp = ws + OFF_ENCQ + ((size_t)lh * 64 * kB + b) * kD + dd;

  for (int step = 0; step < kSteps; ++step) {
    // ---- T14: issue refg loads NOW; consumed in P4 (hidden under P1-P3) ----
    float4 ga0 = *(const float4*)rgp0, gb0 = *(const float4*)(rgp0 + 4);
    float4 ga1 = *(const float4*)rgp1, gb1 = *(const float4*)(rgp1 + 4);
    float4 ga2 = *(const float4*)rgp2, gb2 = *(const float4*)(rgp2 + 4);
    float4 ga3 = *(const float4*)rgp3, gb3 = *(const float4*)(rgp3 + 4);
    float4 ga4 = *(const float4*)rgp4, gb4 = *(const float4*)(rgp4 + 4);
    float4 ga5 = *(const float4*)rgp5, gb5 = *(const float4*)(rgp5 + 4);
    float4 ga6 = *(const float4*)rgp6, gb6 = *(const float4*)(rgp6 + 4);
    float4 ga7 = *(const float4*)rgp7, gb7 = *(const float4*)(rgp7 + 4);
    KEEP4(ga0); KEEP4(gb0); KEEP4(ga1); KEEP4(gb1);
    KEEP4(ga2); KEEP4(gb2); KEEP4(ga3); KEEP4(gb3);
    KEEP4(ga4); KEEP4(gb4); KEEP4(ga5); KEEP4(gb5);
    KEEP4(ga6); KEEP4(gb6); KEEP4(ga7); KEEP4(gb7);
    float eqv[64];   // filled at end of P4 (after refg regs die), consumed in P6
    // ---- P1: gates(2t,2t+1) = (gx or W_ih.x) + W_hh.h ----
    {
      float a0, a1;
      const int row = *s_idx;
      if constexpr (GX) {
        const float2 gx2 = *(const float2*)(GXT + ((size_t)row * kB + b) * 512 + 2 * t);
        a0 = gx2.x; a1 = gx2.y;
      } else {
        if (t < 128) {
          const float* xs = (row == 128) ? dec0 + (size_t)b * 128
                                         : emb + ((size_t)row * kB + b) * kD;
          sm[SM_RED + t] = xs[t];
        }
        __syncthreads();
        a0 = bias0; a1 = bias1;
        const float* wp = WL + 2 * t;
        #pragma unroll 8
        for (int k4 = 0; k4 < 32; ++k4) {
          const float4 x4 = *(const float4*)&sm[SM_RED + k4 * 4];
          const float2 w0 = *(const float2*)(wp + (size_t)(k4 * 4 + 0) * 512);
          const float2 w1 = *(const float2*)(wp + (size_t)(k4 * 4 + 1) * 512);
          const float2 w2 = *(const float2*)(wp + (size_t)(k4 * 4 + 2) * 512);
          const float2 w3 = *(const float2*)(wp + (size_t)(k4 * 4 + 3) * 512);
          a0 += x4.x * w0.x + x4.y * w1.x + x4.z * w2.x + x4.w * w3.x;
          a1 += x4.x * w0.y + x4.y * w1.y + x4.z * w2.y + x4.w * w3.y;
        }
      }
      const float* wp = WHH + 2 * t;
      #pragma unroll 8
      for (int k4 = 0; k4 < 32; ++k4) {
        const float4 h4 = *(const float4*)&sm[SM_H + k4 * 4];
        const float2 w0 = *(const float2*)(wp + (size_t)(k4 * 4 + 0) * 512);
        const float2 w1 = *(const float2*)(wp + (size_t)(k4 * 4 + 1) * 512);
        const float2 w2 = *(const float2*)(wp + (size_t)(k4 * 4 + 2) * 512);
        const float2 w3 = *(const float2*)(wp + (size_t)(k4 * 4 + 3) * 512);
        a0 += h4.x * w0.x + h4.y * w1.x + h4.z * w2.x + h4.w * w3.x;
        a1 += h4.x * w0.y + h4.y * w1.y + h4.z * w2.y + h4.w * w3.y;
      }
      *(float2*)&sm[SM_G + 2 * t] = make_float2(a0, a1);
    }
    __syncthreads();  // B1
    // ---- P2: LSTM cell (t<128); mask update (use_prev only) ----
    if (t < 128) {
      const float gi = sm[SM_G + t];
      const float gf = sm[SM_G + 128 + t];
      const float gg = sm[SM_G + 256 + t];
      const float go = sm[SM_G + 384 + t];
      const float cc = sig_fast(gf) * sm[SM_C + t] + sig_fast(gi) * tanh_fast(gg);
      sm[SM_C + t] = cc;
      sm[SM_H + t] = sig_fast(go) * tanh_fast(cc);
    } else if (t == 128 && step > 0) {
      sm[SM_M + *s_idx] = 1.f;
    }
    __syncthreads();  // B2
    // ---- P3: q_g'[j] = K*(h . wq_g[j] + bq_g) (K folded into WQLG/bqg) ----
    {
      float acc = 0.f;
      #pragma unroll 4
      for (int kk4 = 0; kk4 < 16; ++kk4) {
        const float4 w  = *(const float4*)(WQG + (size_t)kk4 * 1024);
        const float4 h4 = *(const float4*)&sm[SM_H + kq * 64 + kk4 * 4];
        acc += h4.x * w.x + h4.y * w.y + h4.z * w.z + h4.w * w.w;
      }
      acc += __shfl_xor(acc, 1);
      if (!kq) sm[SM_QG + j2] = acc + bqg;
    }
    __syncthreads();  // B3
    // ---- P4: glimpse scores via rcp form: u = vgsum - sum 2v*rcp(exp2(r'+q')+1) ----
    {
      const float4 qa = *(const float4*)&sm[SM_QG + sub * 8];
      const float4 qb = *(const float4*)&sm[SM_QG + sub * 8 + 4];
      const float4 va = *(const float4*)&sm[SM_VG + sub * 8];
      const float4 vb = *(const float4*)&sm[SM_VG + sub * 8 + 4];
      #define P4_ROW(IT, RA, RB)                                            \
      {                                                                     \
        const int l = IT * 16 + wv * 4 + rr;                                \
        float s2;                                                           \
        s2  = va.x * rcp_raw(exp2_raw(RA.x + qa.x) + 1.0f);                 \
        s2 += va.y * rcp_raw(exp2_raw(RA.y + qa.y) + 1.0f);                 \
        s2 += va.z * rcp_raw(exp2_raw(RA.z + qa.z) + 1.0f);                 \
        s2 += va.w * rcp_raw(exp2_raw(RA.w + qa.w) + 1.0f);                 \
        s2 += vb.x * rcp_raw(exp2_raw(RB.x + qb.x) + 1.0f);                 \
        s2 += vb.y * rcp_raw(exp2_raw(RB.y + qb.y) + 1.0f);                 \
        s2 += vb.z * rcp_raw(exp2_raw(RB.z + qb.z) + 1.0f);                 \
        s2 += vb.w * rcp_raw(exp2_raw(RB.w + qb.w) + 1.0f);                 \
        s2 += __shfl_xor(s2, 1); s2 += __shfl_xor(s2, 2);                   \
        s2 += __shfl_xor(s2, 4); s2 += __shfl_xor(s2, 8);                   \
        if (sub == 0) {                                                     \
          float u = vgsum - s2;                                             \
          if (step > 0 && sm[SM_M + l] != 0.f) u = -INFINITY;               \
          sm[SM_U + l] = u;                                                 \
        }                                                                   \
      }
      P4_ROW(0, ga0, gb0) P4_ROW(1, ga1, gb1)
      P4_ROW(2, ga2, gb2) P4_ROW(3, ga3, gb3)
      P4_ROW(4, ga4, gb4) P4_ROW(5, ga5, gb5)
      P4_ROW(6, ga6, gb6) P4_ROW(7, ga7, gb7)
      #undef P4_ROW
    }
    // ---- T14 (ENCQ): refg regs are dead now; issue P6's 64 loads here so they
    // fly across B4 + P5 + B5 (r15 lesson: never overlap with the refg pins) ----
    #pragma unroll
    for (int ll = 0; ll < 64; ++ll) {
      eqv[ll] = eqp[(size_t)ll * kB * kD];
    }
    #pragma unroll
    for (int ll = 0; ll < 64; ++ll) KEEP1(eqv[ll]);
    __syncthreads();  // B4
    // ---- P5: glimpse softmax (wave 0) -> PG ----
    if (t < 64) {
      const float v0 = sm[SM_U + t], v1 = sm[SM_U + 64 + t];
      float m = fmaxf(v0, v1);
      #pragma unroll
      for (int off = 1; off < 64; off <<= 1) m = fmaxf(m, __shfl_xor(m, off, 64));
      const float e0 = __expf(v0 - m), e1 = __expf(v1 - m);
      float ssum = e0 + e1;
      #pragma unroll
      for (int off = 1; off < 64; off <<= 1) ssum += __shfl_xor(ssum, off, 64);
      const float inv = __fdividef(1.0f, ssum);
      sm[SM_PG + t]      = e0 * inv;
      sm[SM_PG + 64 + t] = e1 * inv;
    }
    __syncthreads();  // B5
    // ---- P6: q_p' partials from prefetched encq (K-scaled; p sums to 1) ----
    {
      float acc = 0.f;
      #pragma unroll
      for (int ll = 0; ll < 64; ++ll) {
        acc += sm[SM_PG + lh * 64 + ll] * eqv[ll];
      }
      sm[SM_RED + t] = acc;   // RED[lh*128 + dd]
    }
    __syncthreads();  // B6
    // ---- P8: fold q_p'; pointer scores via rcp form; 10*tanh clip; mask ----
    {
      const float4 r0a = *(const float4*)&sm[SM_RED + sub * 8];
      const float4 r0b = *(const float4*)&sm[SM_RED + sub * 8 + 4];
      const float4 r1a = *(const float4*)&sm[SM_RED + 128 + sub * 8];
      const float4 r1b = *(const float4*)&sm[SM_RED + 128 + sub * 8 + 4];
      const float4 qa = make_float4(r0a.x + r1a.x, r0a.y + r1a.y,
                                    r0a.z + r1a.z, r0a.w + r1a.w);
      const float4 qb = make_float4(r0b.x + r1b.x, r0b.y + r1b.y,
                                    r0b.z + r1b.z, r0b.w + r1b.w);
      const float4 va = *(const float4*)&sm[SM_VP + sub * 8];
      const float4 vb = *(const float4*)&sm[SM_VP + sub * 8 + 4];
      #pragma unroll
      for (int it = 0; it < 8; ++it) {
        const int l = it * 16 + wv * 4 + rr;
        const float4 ra = *(const float4*)&sm[SM_REFP + (it * 512 + t) * 4];
        const float4 rb = *(const float4*)&sm[SM_REFP + (it * 512 + 256 + t) * 4];
        float s2;
        s2  = va.x * rcp_raw(exp2_raw(ra.x + qa.x) + 1.0f);
        s2 += va.y * rcp_raw(exp2_raw(ra.y + qa.y) + 1.0f);
        s2 += va.z * rcp_raw(exp2_raw(ra.z + qa.z) + 1.0f);
        s2 += va.w * rcp_raw(exp2_raw(ra.w + qa.w) + 1.0f);
        s2 += vb.x * rcp_raw(exp2_raw(rb.x + qb.x) + 1.0f);
        s2 += vb.y * rcp_raw(exp2_raw(rb.y + qb.y) + 1.0f);
        s2 += vb.z * rcp_raw(exp2_raw(rb.z + qb.z) + 1.0f);
        s2 += vb.w * rcp_raw(exp2_raw(rb.w + qb.w) + 1.0f);
        s2 += __shfl_xor(s2, 1); s2 += __shfl_xor(s2, 2);
        s2 += __shfl_xor(s2, 4); s2 += __shfl_xor(s2, 8);
        if (sub == 0) {
          float uu = 10.f * tanh_fast(vpsum - s2);
          if (step > 0 && sm[SM_M + l] != 0.f) uu = -INFINITY;
          sm[SM_U + l] = uu;
        }
      }
    }
    __syncthreads();  // B7
    // ---- P9: pointer softmax + argmax; write probs + idx directly ----
    if (t < 64) {
      const float v0 = sm[SM_U + t], v1 = sm[SM_U + 64 + t];
      float m = fmaxf(v0, v1);
      #pragma unroll
      for (int off = 1; off < 64; off <<= 1) m = fmaxf(m, __shfl_xor(m, off, 64));
      const float e0 = __expf(v0 - m), e1 = __expf(v1 - m);
      float ssum = e0 + e1;
      #pragma unroll
      for (int off = 1; off < 64; off <<= 1) ssum += __shfl_xor(ssum, off, 64);
      const float inv = __fdividef(1.0f, ssum);
      float* orow = out + ((size_t)step * kB + b) * kL;
      orow[t]      = e0 * inv;
      orow[64 + t] = e1 * inv;
      float av; int ai;
      if (v0 >= v1) { av = v0; ai = t; } else { av = v1; ai = t + 64; }
      #pragma unroll
      for (int off = 1; off < 64; off <<= 1) {
        const float ov = __shfl_xor(av, off, 64);
        const int   oi = __shfl_xor(ai, off, 64);
        if (ov > av || (ov == av && oi < ai)) { av = ov; ai = oi; }
      }
      if (t == 0) {
        *s_idx = ai;
        out[OUT_IDX_OFF + (size_t)step * kB + b] = (float)ai;
      }
    }
    __syncthreads();  // B8
  }
}

extern "C" void kernel_launch(void* const* d_in, const int* in_sizes, int n_in,
                              void* d_out, int out_size, void* d_ws, size_t ws_size,
                              hipStream_t stream) {
  (void)in_sizes; (void)n_in; (void)out_size;
  const float* dec0 = (const float*)d_in[0];
  const float* emb  = (const float*)d_in[1];
  const float* h0   = (const float*)d_in[2];
  const float* c0   = (const float*)d_in[3];
  const float* enc  = (const float*)d_in[4];
  const float* w_ih = (const float*)d_in[5];
  const float* w_hh = (const float*)d_in[6];
  const float* b_ih = (const float*)d_in[7];
  const float* b_hh = (const float*)d_in[8];
  const float* wq_p = (const float*)d_in[9];
  const float* bq_p = (const float*)d_in[10];
  const float* wr_p = (const float*)d_in[11];
  const float* br_p = (const float*)d_in[12];
  const float* v_p  = (const float*)d_in[13];
  const float* wq_g = (const float*)d_in[14];
  const float* bq_g = (const float*)d_in[15];
  const float* wr_g = (const float*)d_in[16];
  const float* br_g = (const float*)d_in[17];
  const float* v_g  = (const float*)d_in[18];
  float* ws  = (float*)d_ws;
  float* out = (float*)d_out;

  const bool gx_ok = ws_size >= kTotalGx * 4;   // ~237 MB with the gx table

  prep_weights<<<dim3(64), dim3(256), 0, stream>>>(
      w_ih, w_hh, b_ih, b_hh, wq_p, wq_g, wr_p, wr_g, ws);
  prep_mm<<<dim3(1024, 3), dim3(256), 24576 * 4, stream>>>(
      enc, br_g, br_p, bq_p, ws);
  if (gx_ok) {
    prep_gx<<<dim3(1032, 4), dim3(256), 24576 * 4, stream>>>(emb, dec0, ws);
    decode_main<true><<<dim3(512), dim3(256), SM_TOTAL * 4, stream>>>(
        dec0, emb, h0, c0, bq_g, v_p, v_g, ws, out);
  } else {
    decode_main<false><<<dim3(512), dim3(256), SM_TOTAL * 4, stream>>>(
        dec0, emb, h0, c0, bq_g, v_p, v_g, ws, out);
  }
}

// Round 18
// 4309.244 us; speedup vs baseline: 1.5231x; 1.5231x over previous
//
#include <hip/hip_runtime.h>
#include <math.h>

namespace {

constexpr int kB = 512;
constexpr int kL = 128;
constexpr int kD = 128;
constexpr int kSteps = 126;   // L - 2
constexpr float kK = 2.8853900817779268f;  // 2*log2(e): exp(2y) = exp2(K*y)

// ---- workspace layout (float offsets) ----
constexpr size_t OFF_WL   = 0;          // [256][512] k-major: k<128 w_ih, else w_hh
constexpr size_t OFF_BIAS = 131072;     // [512] b_ih + b_hh
constexpr size_t OFF_WQLG = 131584;     // [16][256][4] lane-matched K*wq_g (P3)
constexpr size_t OFF_WQTP = 147968;     // [128][128] wq_p k-major (for encq prep)
constexpr size_t OFF_WRTG = 164352;     // [128][128] wr_g k-major
constexpr size_t OFF_WRTP = 180736;     // [128][128] wr_p k-major
constexpr size_t OFF_WIHT = 197120;     // [128][512] w_ih k-major (prep_gx)
constexpr size_t OFF_REFG = 262656;                                 // [L][B][D], K-scaled
constexpr size_t OFF_REFP = OFF_REFG + (size_t)kL * kB * kD;        // K-scaled
constexpr size_t OFF_ENCQ = OFF_REFP + (size_t)kL * kB * kD;        // K*(enc@wq_p^T+bq_p)
constexpr size_t kTotalNoGx = OFF_ENCQ + (size_t)kL * kB * kD;
constexpr size_t OFF_GX   = kTotalNoGx;                             // [129*512][512]
constexpr size_t kTotalGx = OFF_GX + (size_t)129 * kB * 512;        // ~237 MB

constexpr size_t OUT_IDX_OFF = (size_t)kSteps * kB * kL;  // probs first, then idx

// ---- dynamic LDS layout for decode_main (float offsets), ~73 KB ----
constexpr int SM_REFP = 0;      // [8 it][2 slot][256 t][4] = 16384 floats, conflict-free
constexpr int SM_H    = 16384;  // [128]
constexpr int SM_C    = 16512;  // [128]
constexpr int SM_G    = 16640;  // [512] gates
constexpr int SM_RED  = 17152;  // [256] P6 q_p partials (also x-staging in non-GX tier)
constexpr int SM_QG   = 17408;  // [128]
constexpr int SM_U    = 17536;  // [128]
constexpr int SM_PG   = 17664;  // [128] glimpse probs
constexpr int SM_M    = 17792;  // [128] mask
constexpr int SM_VG   = 17920;  // [128] holds 2*v_g
constexpr int SM_VP   = 18048;  // [128] holds 2*v_p
constexpr int SM_IDX  = 18176;  // int
constexpr int SM_TOTAL= 18180;

// fast transcendentals
__device__ __forceinline__ float tanh_fast(float x) {
  return 1.0f - __fdividef(2.0f, __expf(2.0f * x) + 1.0f);
}
__device__ __forceinline__ float sig_fast(float x) {
  return __fdividef(1.0f, 1.0f + __expf(-x));
}
// raw single-instruction transcendentals (guaranteed lowering)
__device__ __forceinline__ float exp2_raw(float x) {
  float r; asm("v_exp_f32 %0, %1" : "=v"(r) : "v"(x)); return r;
}
__device__ __forceinline__ float rcp_raw(float x) {
  float r; asm("v_rcp_f32 %0, %1" : "=v"(r) : "v"(x)); return r;
}

// anchor values in VGPRs at this program point (rule #17/#18)
#define KEEP4(v) asm volatile("" : "+v"(v.x), "+v"(v.y), "+v"(v.z), "+v"(v.w))
#define KEEP1(v) asm volatile("" : "+v"(v))

} // namespace

// ---------- one-time: weight relayouts + fused bias ----------
extern "C" __global__ void prep_weights(
    const float* __restrict__ w_ih, const float* __restrict__ w_hh,
    const float* __restrict__ b_ih, const float* __restrict__ b_hh,
    const float* __restrict__ wq_p, const float* __restrict__ wq_g,
    const float* __restrict__ wr_p, const float* __restrict__ wr_g,
    float* __restrict__ ws) {
  const int tid = blockIdx.x * blockDim.x + threadIdx.x;
  const int nth = gridDim.x * blockDim.x;
  for (int i = tid; i < 256 * 512; i += nth) {
    const int k = i >> 9, g = i & 511;
    ws[OFF_WL + i] = (k < 128) ? w_ih[g * 128 + k] : w_hh[g * 128 + (k - 128)];
  }
  for (int i = tid; i < 512; i += nth) ws[OFF_BIAS + i] = b_ih[i] + b_hh[i];
  // WQLG: K-scaled so P3 produces q_g' = K*q_g directly
  for (int i = tid; i < 16384; i += nth) {
    const int e = i & 3, rest = i >> 2;
    const int kq = rest & 1, j = (rest >> 1) & 127, kk4 = rest >> 8;
    const int k = kq * 64 + kk4 * 4 + e;
    ws[OFF_WQLG + i] = kK * wq_g[j * 128 + k];
  }
  for (int i = tid; i < 128 * 512; i += nth) {
    const int k = i >> 9, g = i & 511;
    ws[OFF_WIHT + i] = w_ih[g * 128 + k];
  }
  for (int i = tid; i < 128 * 128; i += nth) {
    const int k = i >> 7, j = i & 127;
    ws[OFF_WQTP + i] = wq_p[j * 128 + k];
    ws[OFF_WRTG + i] = wr_g[j * 128 + k];
    ws[OFF_WRTP + i] = wr_p[j * 128 + k];
  }
}

// ---------- one-time tiled GEMM: {ref_g, ref_p, encq} = K*(enc @ W + bias) ----------
extern "C" __global__ __launch_bounds__(256) void prep_mm(
    const float* __restrict__ enc,
    const float* __restrict__ br_g, const float* __restrict__ br_p,
    const float* __restrict__ bq_p,
    float* __restrict__ ws) {
  extern __shared__ float lds[];
  float* wT = lds;          // [128 k][128 j]
  float* sx = lds + 16384;  // [64 r][128 k]
  const int t = threadIdx.x;
  const int table = blockIdx.y;
  const size_t wOff = (table == 0) ? OFF_WRTG : (table == 1) ? OFF_WRTP : OFF_WQTP;
  const size_t oOff = (table == 0) ? OFF_REFG : (table == 1) ? OFF_REFP : OFF_ENCQ;
  const float* bias = (table == 0) ? br_g : (table == 1) ? br_p : bq_p;
  for (int i = t; i < 16384; i += 256) wT[i] = ws[wOff + i];
  const size_t r0 = (size_t)blockIdx.x * 64;   // rid = l*512 + b
  for (int i = t; i < 8192; i += 256) sx[i] = enc[r0 * 128 + i];
  __syncthreads();
  const int j0 = (t & 31) * 4, rg = t >> 5;
  float4 acc[8];
  const float4 b4 = *(const float4*)(bias + j0);
  #pragma unroll
  for (int r = 0; r < 8; ++r) acc[r] = b4;
  for (int k4 = 0; k4 < 32; ++k4) {
    const float4 w0 = *(const float4*)&wT[(k4 * 4 + 0) * 128 + j0];
    const float4 w1 = *(const float4*)&wT[(k4 * 4 + 1) * 128 + j0];
    const float4 w2 = *(const float4*)&wT[(k4 * 4 + 2) * 128 + j0];
    const float4 w3 = *(const float4*)&wT[(k4 * 4 + 3) * 128 + j0];
    #pragma unroll
    for (int r = 0; r < 8; ++r) {
      const float4 xv = *(const float4*)&sx[(rg * 8 + r) * 128 + k4 * 4];
      acc[r].x += xv.x * w0.x + xv.y * w1.x + xv.z * w2.x + xv.w * w3.x;
      acc[r].y += xv.x * w0.y + xv.y * w1.y + xv.z * w2.y + xv.w * w3.y;
      acc[r].z += xv.x * w0.z + xv.y * w1.z + xv.z * w2.z + xv.w * w3.z;
      acc[r].w += xv.x * w0.w + xv.y * w1.w + xv.z * w2.w + xv.w * w3.w;
    }
  }
  #pragma unroll
  for (int r = 0; r < 8; ++r) {
    acc[r].x *= kK; acc[r].y *= kK; acc[r].z *= kK; acc[r].w *= kK;
    *(float4*)&ws[oOff + (r0 + rg * 8 + r) * 128 + j0] = acc[r];
  }
}

// ---------- one-time tiled GEMM: gx[rid][g] = x_rid . w_ih[g,:] + bias[g] ----------
extern "C" __global__ __launch_bounds__(256) void prep_gx(
    const float* __restrict__ emb, const float* __restrict__ dec0,
    float* __restrict__ ws) {
  extern __shared__ float lds[];
  float* wT = lds;          // [128 k][128 g]
  float* sx = lds + 16384;  // [64 r][128 k]
  const int t = threadIdx.x;
  const int g0 = blockIdx.y * 128;
  for (int i = t; i < 16384; i += 256) {
    wT[i] = ws[OFF_WIHT + (size_t)(i >> 7) * 512 + g0 + (i & 127)];
  }
  const size_t r0 = (size_t)blockIdx.x * 64;
  for (int i = t; i < 8192; i += 256) {
    const size_t rid = r0 + (i >> 7);
    const int c = i & 127;
    sx[i] = (rid < 65536) ? emb[rid * 128 + c] : dec0[(rid - 65536) * 128 + c];
  }
  __syncthreads();
  const int j0 = (t & 31) * 4, rg = t >> 5;
  float4 acc[8];
  const float4 b4 = *(const float4*)(ws + OFF_BIAS + g0 + j0);
  #pragma unroll
  for (int r = 0; r < 8; ++r) acc[r] = b4;
  for (int k4 = 0; k4 < 32; ++k4) {
    const float4 w0 = *(const float4*)&wT[(k4 * 4 + 0) * 128 + j0];
    const float4 w1 = *(const float4*)&wT[(k4 * 4 + 1) * 128 + j0];
    const float4 w2 = *(const float4*)&wT[(k4 * 4 + 2) * 128 + j0];
    const float4 w3 = *(const float4*)&wT[(k4 * 4 + 3) * 128 + j0];
    #pragma unroll
    for (int r = 0; r < 8; ++r) {
      const float4 xv = *(const float4*)&sx[(rg * 8 + r) * 128 + k4 * 4];
      acc[r].x += xv.x * w0.x + xv.y * w1.x + xv.z * w2.x + xv.w * w3.x;
      acc[r].y += xv.x * w0.y + xv.y * w1.y + xv.z * w2.y + xv.w * w3.y;
      acc[r].z += xv.x * w0.z + xv.y * w1.z + xv.z * w2.z + xv.w * w3.z;
      acc[r].w += xv.x * w0.w + xv.y * w1.w + xv.z * w2.w + xv.w * w3.w;
    }
  }
  #pragma unroll
  for (int r = 0; r < 8; ++r) {
    *(float4*)&ws[OFF_GX + (r0 + rg * 8 + r) * 512 + g0 + j0] = acc[r];
  }
}

// ---------- persistent decode: one block per batch element, 256 threads, 2/CU ----------
// r16 + HALF-size ENCQ prefetch (32 regs, issued end-of-P4 where refg regs die).
// r15/r17 lesson: a 64-reg prefetch cannot fit under the 128-VGPR budget; 32 can.
template <bool GX>
__global__ __launch_bounds__(256, 2) void decode_main(
    const float* __restrict__ dec0, const float* __restrict__ emb,
    const float* __restrict__ h0,   const float* __restrict__ c0,
    const float* __restrict__ bq_g, const float* __restrict__ v_p,
    const float* __restrict__ v_g,
    const float* __restrict__ ws, float* __restrict__ out) {
  extern __shared__ float sm[];
  int* s_idx = (int*)(sm + SM_IDX);

  const int t = threadIdx.x;
  const int b = blockIdx.x;
  const int wv = t >> 6, lane = t & 63;
  const int sub = lane & 15, rr = lane >> 4;
  const int j2 = t >> 1, kq = t & 1;     // P3 mapping
  const int lh = t >> 7, dd = t & 127;   // P6 mapping

  // ---- startup: ref_p (K-scaled) -> LDS, conflict-free split-float4 slots ----
  #pragma unroll
  for (int it = 0; it < 8; ++it) {
    const int l = it * 16 + wv * 4 + rr;
    const float* src = ws + OFF_REFP + ((size_t)l * kB + b) * kD + sub * 8;
    *(float4*)&sm[SM_REFP + (it * 512 + t) * 4]       = *(const float4*)src;
    *(float4*)&sm[SM_REFP + (it * 512 + 256 + t) * 4] = *(const float4*)(src + 4);
  }
  if (t < 128) {
    sm[SM_H + t]  = h0[b * 128 + t];
    sm[SM_C + t]  = c0[b * 128 + t];
    sm[SM_M + t]  = (t < 2) ? 1.f : 0.f;   // indices 0,1 pre-visited
    sm[SM_VG + t] = 2.0f * v_g[t];         // 2v tables for the rcp form
    sm[SM_VP + t] = 2.0f * v_p[t];
  }
  if (t == 0) *s_idx = 128;   // sentinel: dec0 row
  const float bqg = kK * bq_g[j2];
  const float bias0 = ws[OFF_BIAS + 2 * t];
  const float bias1 = ws[OFF_BIAS + 2 * t + 1];
  __syncthreads();

  // vsum scalars (Σv = 0.5 * Σ(2v); broadcast LDS reads)
  float vgsum = 0.f, vpsum = 0.f;
  #pragma unroll 8
  for (int i = 0; i < 128; i += 4) {
    const float4 a = *(const float4*)&sm[SM_VG + i];
    const float4 p = *(const float4*)&sm[SM_VP + i];
    vgsum += a.x + a.y + a.z + a.w;
    vpsum += p.x + p.y + p.z + p.w;
  }
  vgsum *= 0.5f; vpsum *= 0.5f;

  const float* WL  = ws + OFF_WL;
  const float* WHH = WL + 128 * 512;
  const float* WQG = ws + OFF_WQLG + 4 * t;
  const float* REFG = ws + OFF_REFG;
  const float* ENCQ = ws + OFF_ENCQ;
  const float* GXT  = ws + OFF_GX;

  // per-it refg source pointers (step-invariant addresses)
  const float* rgp0 = REFG + ((size_t)( 0 + wv * 4 + rr) * kB + b) * kD + sub * 8;
  const float* rgp1 = REFG + ((size_t)(16 + wv * 4 + rr) * kB + b) * kD + sub * 8;
  const float* rgp2 = REFG + ((size_t)(32 + wv * 4 + rr) * kB + b) * kD + sub * 8;
  const float* rgp3 = REFG + ((size_t)(48 + wv * 4 + rr) * kB + b) * kD + sub * 8;
  const float* rgp4 = REFG + ((size_t)(64 + wv * 4 + rr) * kB + b) * kD + sub * 8;
  const float* rgp5 = REFG + ((size_t)(80 + wv * 4 + rr) * kB + b) * kD + sub * 8;
  const float* rgp6 = REFG + ((size_t)(96 + wv * 4 + rr) * kB + b) * kD + sub * 8;
  const float* rgp7 = REFG + ((size_t)(112 + wv * 4 + rr) * kB + b) * kD + sub * 8;
  // ENCQ source base (step-invariant): eqp[ll * kB*kD] = ENCQ[(lh*64+ll)*kB + b][dd]
  const float* eqp = ENCQ + ((size_t)lh * 64 * kB + b) * kD + dd;

  for (int step = 0; step < kSteps; ++step) {
    // ---- T14: issue refg loads NOW; consumed in P4 (hidden under P1-P3) ----
    float4 ga0 = *(const float4*)rgp0, gb0 = *(const float4*)(rgp0 + 4);
    float4 ga1 = *(const float4*)rgp1, gb1 = *(const float4*)(rgp1 + 4);
    float4 ga2 = *(const float4*)rgp2, gb2 = *(const float4*)(rgp2 + 4);
    float4 ga3 = *(const float4*)rgp3, gb3 = *(const float4*)(rgp3 + 4);
    float4 ga4 = *(const float4*)rgp4, gb4 = *(const float4*)(rgp4 + 4);
    float4 ga5 = *(const float4*)rgp5, gb5 = *(const float4*)(rgp5 + 4);
    float4 ga6 = *(const float4*)rgp6, gb6 = *(const float4*)(rgp6 + 4);
    float4 ga7 = *(const float4*)rgp7, gb7 = *(const float4*)(rgp7 + 4);
    KEEP4(ga0); KEEP4(gb0); KEEP4(ga1); KEEP4(gb1);
    KEEP4(ga2); KEEP4(gb2); KEEP4(ga3); KEEP4(gb3);
    KEEP4(ga4); KEEP4(gb4); KEEP4(ga5); KEEP4(gb5);
    KEEP4(ga6); KEEP4(gb6); KEEP4(ga7); KEEP4(gb7);
    float eqv[32];   // first half of P6's inputs; filled end-of-P4, used in P6
    // ---- P1: gates(2t,2t+1) = (gx or W_ih.x) + W_hh.h ----
    {
      float a0, a1;
      const int row = *s_idx;
      if constexpr (GX) {
        const float2 gx2 = *(const float2*)(GXT + ((size_t)row * kB + b) * 512 + 2 * t);
        a0 = gx2.x; a1 = gx2.y;
      } else {
        if (t < 128) {
          const float* xs = (row == 128) ? dec0 + (size_t)b * 128
                                         : emb + ((size_t)row * kB + b) * kD;
          sm[SM_RED + t] = xs[t];
        }
        __syncthreads();
        a0 = bias0; a1 = bias1;
        const float* wp = WL + 2 * t;
        #pragma unroll 8
        for (int k4 = 0; k4 < 32; ++k4) {
          const float4 x4 = *(const float4*)&sm[SM_RED + k4 * 4];
          const float2 w0 = *(const float2*)(wp + (size_t)(k4 * 4 + 0) * 512);
          const float2 w1 = *(const float2*)(wp + (size_t)(k4 * 4 + 1) * 512);
          const float2 w2 = *(const float2*)(wp + (size_t)(k4 * 4 + 2) * 512);
          const float2 w3 = *(const float2*)(wp + (size_t)(k4 * 4 + 3) * 512);
          a0 += x4.x * w0.x + x4.y * w1.x + x4.z * w2.x + x4.w * w3.x;
          a1 += x4.x * w0.y + x4.y * w1.y + x4.z * w2.y + x4.w * w3.y;
        }
      }
      const float* wp = WHH + 2 * t;
      #pragma unroll 8
      for (int k4 = 0; k4 < 32; ++k4) {
        const float4 h4 = *(const float4*)&sm[SM_H + k4 * 4];
        const float2 w0 = *(const float2*)(wp + (size_t)(k4 * 4 + 0) * 512);
        const float2 w1 = *(const float2*)(wp + (size_t)(k4 * 4 + 1) * 512);
        const float2 w2 = *(const float2*)(wp + (size_t)(k4 * 4 + 2) * 512);
        const float2 w3 = *(const float2*)(wp + (size_t)(k4 * 4 + 3) * 512);
        a0 += h4.x * w0.x + h4.y * w1.x + h4.z * w2.x + h4.w * w3.x;
        a1 += h4.x * w0.y + h4.y * w1.y + h4.z * w2.y + h4.w * w3.y;
      }
      *(float2*)&sm[SM_G + 2 * t] = make_float2(a0, a1);
    }
    __syncthreads();  // B1
    // ---- P2: LSTM cell (t<128); mask update (use_prev only) ----
    if (t < 128) {
      const float gi = sm[SM_G + t];
      const float gf = sm[SM_G + 128 + t];
      const float gg = sm[SM_G + 256 + t];
      const float go = sm[SM_G + 384 + t];
      const float cc = sig_fast(gf) * sm[SM_C + t] + sig_fast(gi) * tanh_fast(gg);
      sm[SM_C + t] = cc;
      sm[SM_H + t] = sig_fast(go) * tanh_fast(cc);
    } else if (t == 128 && step > 0) {
      sm[SM_M + *s_idx] = 1.f;
    }
    __syncthreads();  // B2
    // ---- P3: q_g'[j] = K*(h . wq_g[j] + bq_g) (K folded into WQLG/bqg) ----
    {
      float acc = 0.f;
      #pragma unroll 4
      for (int kk4 = 0; kk4 < 16; ++kk4) {
        const float4 w  = *(const float4*)(WQG + (size_t)kk4 * 1024);
        const float4 h4 = *(const float4*)&sm[SM_H + kq * 64 + kk4 * 4];
        acc += h4.x * w.x + h4.y * w.y + h4.z * w.z + h4.w * w.w;
      }
      acc += __shfl_xor(acc, 1);
      if (!kq) sm[SM_QG + j2] = acc + bqg;
    }
    __syncthreads();  // B3
    // ---- P4: glimpse scores via rcp form: u = vgsum - sum 2v*rcp(exp2(r'+q')+1) ----
    {
      const float4 qa = *(const float4*)&sm[SM_QG + sub * 8];
      const float4 qb = *(const float4*)&sm[SM_QG + sub * 8 + 4];
      const float4 va = *(const float4*)&sm[SM_VG + sub * 8];
      const float4 vb = *(const float4*)&sm[SM_VG + sub * 8 + 4];
      #define P4_ROW(IT, RA, RB)                                            \
      {                                                                     \
        const int l = IT * 16 + wv * 4 + rr;                                \
        float s2;                                                           \
        s2  = va.x * rcp_raw(exp2_raw(RA.x + qa.x) + 1.0f);                 \
        s2 += va.y * rcp_raw(exp2_raw(RA.y + qa.y) + 1.0f);                 \
        s2 += va.z * rcp_raw(exp2_raw(RA.z + qa.z) + 1.0f);                 \
        s2 += va.w * rcp_raw(exp2_raw(RA.w + qa.w) + 1.0f);                 \
        s2 += vb.x * rcp_raw(exp2_raw(RB.x + qb.x) + 1.0f);                 \
        s2 += vb.y * rcp_raw(exp2_raw(RB.y + qb.y) + 1.0f);                 \
        s2 += vb.z * rcp_raw(exp2_raw(RB.z + qb.z) + 1.0f);                 \
        s2 += vb.w * rcp_raw(exp2_raw(RB.w + qb.w) + 1.0f);                 \
        s2 += __shfl_xor(s2, 1); s2 += __shfl_xor(s2, 2);                   \
        s2 += __shfl_xor(s2, 4); s2 += __shfl_xor(s2, 8);                   \
        if (sub == 0) {                                                     \
          float u = vgsum - s2;                                             \
          if (step > 0 && sm[SM_M + l] != 0.f) u = -INFINITY;               \
          sm[SM_U + l] = u;                                                 \
        }                                                                   \
      }
      P4_ROW(0, ga0, gb0) P4_ROW(1, ga1, gb1)
      P4_ROW(2, ga2, gb2) P4_ROW(3, ga3, gb3)
      P4_ROW(4, ga4, gb4) P4_ROW(5, ga5, gb5)
      P4_ROW(6, ga6, gb6) P4_ROW(7, ga7, gb7)
      #undef P4_ROW
    }
    // ---- T14 (ENCQ, half): refg regs dead; issue 32 loads to fly over B4+P5+B5 ----
    #pragma unroll
    for (int ll = 0; ll < 32; ++ll) {
      eqv[ll] = eqp[(size_t)ll * kB * kD];
    }
    #pragma unroll
    for (int ll = 0; ll < 32; ++ll) KEEP1(eqv[ll]);
    __syncthreads();  // B4
    // ---- P5: glimpse softmax (wave 0) -> PG ----
    if (t < 64) {
      const float v0 = sm[SM_U + t], v1 = sm[SM_U + 64 + t];
      float m = fmaxf(v0, v1);
      #pragma unroll
      for (int off = 1; off < 64; off <<= 1) m = fmaxf(m, __shfl_xor(m, off, 64));
      const float e0 = __expf(v0 - m), e1 = __expf(v1 - m);
      float ssum = e0 + e1;
      #pragma unroll
      for (int off = 1; off < 64; off <<= 1) ssum += __shfl_xor(ssum, off, 64);
      const float inv = __fdividef(1.0f, ssum);
      sm[SM_PG + t]      = e0 * inv;
      sm[SM_PG + 64 + t] = e1 * inv;
    }
    __syncthreads();  // B5
    // ---- P6: q_p' partials; first 32 from prefetched regs, rest streamed ----
    {
      float acc = 0.f;
      #pragma unroll
      for (int ll = 0; ll < 32; ++ll) {
        acc += sm[SM_PG + lh * 64 + ll] * eqv[ll];
      }
      #pragma unroll 8
      for (int ll = 32; ll < 64; ++ll) {
        acc += sm[SM_PG + lh * 64 + ll] * eqp[(size_t)ll * kB * kD];
      }
      sm[SM_RED + t] = acc;   // RED[lh*128 + dd]
    }
    __syncthreads();  // B6
    // ---- P8: fold q_p'; pointer scores via rcp form; 10*tanh clip; mask ----
    {
      const float4 r0a = *(const float4*)&sm[SM_RED + sub * 8];
      const float4 r0b = *(const float4*)&sm[SM_RED + sub * 8 + 4];
      const float4 r1a = *(const float4*)&sm[SM_RED + 128 + sub * 8];
      const float4 r1b = *(const float4*)&sm[SM_RED + 128 + sub * 8 + 4];
      const float4 qa = make_float4(r0a.x + r1a.x, r0a.y + r1a.y,
                                    r0a.z + r1a.z, r0a.w + r1a.w);
      const float4 qb = make_float4(r0b.x + r1b.x, r0b.y + r1b.y,
                                    r0b.z + r1b.z, r0b.w + r1b.w);
      const float4 va = *(const float4*)&sm[SM_VP + sub * 8];
      const float4 vb = *(const float4*)&sm[SM_VP + sub * 8 + 4];
      #pragma unroll
      for (int it = 0; it < 8; ++it) {
        const int l = it * 16 + wv * 4 + rr;
        const float4 ra = *(const float4*)&sm[SM_REFP + (it * 512 + t) * 4];
        const float4 rb = *(const float4*)&sm[SM_REFP + (it * 512 + 256 + t) * 4];
        float s2;
        s2  = va.x * rcp_raw(exp2_raw(ra.x + qa.x) + 1.0f);
        s2 += va.y * rcp_raw(exp2_raw(ra.y + qa.y) + 1.0f);
        s2 += va.z * rcp_raw(exp2_raw(ra.z + qa.z) + 1.0f);
        s2 += va.w * rcp_raw(exp2_raw(ra.w + qa.w) + 1.0f);
        s2 += vb.x * rcp_raw(exp2_raw(rb.x + qb.x) + 1.0f);
        s2 += vb.y * rcp_raw(exp2_raw(rb.y + qb.y) + 1.0f);
        s2 += vb.z * rcp_raw(exp2_raw(rb.z + qb.z) + 1.0f);
        s2 += vb.w * rcp_raw(exp2_raw(rb.w + qb.w) + 1.0f);
        s2 += __shfl_xor(s2, 1); s2 += __shfl_xor(s2, 2);
        s2 += __shfl_xor(s2, 4); s2 += __shfl_xor(s2, 8);
        if (sub == 0) {
          float uu = 10.f * tanh_fast(vpsum - s2);
          if (step > 0 && sm[SM_M + l] != 0.f) uu = -INFINITY;
          sm[SM_U + l] = uu;
        }
      }
    }
    __syncthreads();  // B7
    // ---- P9: pointer softmax + argmax; write probs + idx directly ----
    if (t < 64) {
      const float v0 = sm[SM_U + t], v1 = sm[SM_U + 64 + t];
      float m = fmaxf(v0, v1);
      #pragma unroll
      for (int off = 1; off < 64; off <<= 1) m = fmaxf(m, __shfl_xor(m, off, 64));
      const float e0 = __expf(v0 - m), e1 = __expf(v1 - m);
      float ssum = e0 + e1;
      #pragma unroll
      for (int off = 1; off < 64; off <<= 1) ssum += __shfl_xor(ssum, off, 64);
      const float inv = __fdividef(1.0f, ssum);
      float* orow = out + ((size_t)step * kB + b) * kL;
      orow[t]      = e0 * inv;
      orow[64 + t] = e1 * inv;
      float av; int ai;
      if (v0 >= v1) { av = v0; ai = t; } else { av = v1; ai = t + 64; }
      #pragma unroll
      for (int off = 1; off < 64; off <<= 1) {
        const float ov = __shfl_xor(av, off, 64);
        const int   oi = __shfl_xor(ai, off, 64);
        if (ov > av || (ov == av && oi < ai)) { av = ov; ai = oi; }
      }
      if (t == 0) {
        *s_idx = ai;
        out[OUT_IDX_OFF + (size_t)step * kB + b] = (float)ai;
      }
    }
    __syncthreads();  // B8
  }
}

extern "C" void kernel_launch(void* const* d_in, const int* in_sizes, int n_in,
                              void* d_out, int out_size, void* d_ws, size_t ws_size,
                              hipStream_t stream) {
  (void)in_sizes; (void)n_in; (void)out_size;
  const float* dec0 = (const float*)d_in[0];
  const float* emb  = (const float*)d_in[1];
  const float* h0   = (const float*)d_in[2];
  const float* c0   = (const float*)d_in[3];
  const float* enc  = (const float*)d_in[4];
  const float* w_ih = (const float*)d_in[5];
  const float* w_hh = (const float*)d_in[6];
  const float* b_ih = (const float*)d_in[7];
  const float* b_hh = (const float*)d_in[8];
  const float* wq_p = (const float*)d_in[9];
  const float* bq_p = (const float*)d_in[10];
  const float* wr_p = (const float*)d_in[11];
  const float* br_p = (const float*)d_in[12];
  const float* v_p  = (const float*)d_in[13];
  const float* wq_g = (const float*)d_in[14];
  const float* bq_g = (const float*)d_in[15];
  const float* wr_g = (const float*)d_in[16];
  const float* br_g = (const float*)d_in[17];
  const float* v_g  = (const float*)d_in[18];
  float* ws  = (float*)d_ws;
  float* out = (float*)d_out;

  const bool gx_ok = ws_size >= kTotalGx * 4;   // ~237 MB with the gx table

  prep_weights<<<dim3(64), dim3(256), 0, stream>>>(
      w_ih, w_hh, b_ih, b_hh, wq_p, wq_g, wr_p, wr_g, ws);
  prep_mm<<<dim3(1024, 3), dim3(256), 24576 * 4, stream>>>(
      enc, br_g, br_p, bq_p, ws);
  if (gx_ok) {
    prep_gx<<<dim3(1032, 4), dim3(256), 24576 * 4, stream>>>(emb, dec0, ws);
    decode_main<true><<<dim3(512), dim3(256), SM_TOTAL * 4, stream>>>(
        dec0, emb, h0, c0, bq_g, v_p, v_g, ws, out);
  } else {
    decode_main<false><<<dim3(512), dim3(256), SM_TOTAL * 4, stream>>>(
        dec0, emb, h0, c0, bq_g, v_p, v_g, ws, out);
  }
}

// Round 19
// 3458.253 us; speedup vs baseline: 1.8978x; 1.2461x over previous
//
#include <hip/hip_runtime.h>
#include <math.h>

namespace {

constexpr int kB = 512;
constexpr int kL = 128;
constexpr int kD = 128;
constexpr int kSteps = 126;   // L - 2
constexpr float kK = 2.8853900817779268f;  // 2*log2(e): exp(2y) = exp2(K*y)

// ---- workspace layout (float offsets) ----
constexpr size_t OFF_WL   = 0;          // [256][512] k-major: k<128 w_ih, else w_hh
constexpr size_t OFF_BIAS = 131072;     // [512] b_ih + b_hh
constexpr size_t OFF_WQLG = 131584;     // [16][256][4] lane-matched K*wq_g (P3)
constexpr size_t OFF_WQTP = 147968;     // [128][128] wq_p k-major (for encq prep)
constexpr size_t OFF_WRTG = 164352;     // [128][128] wr_g k-major
constexpr size_t OFF_WRTP = 180736;     // [128][128] wr_p k-major
constexpr size_t OFF_WIHT = 197120;     // [128][512] w_ih k-major (prep_gx)
constexpr size_t OFF_REFG = 262656;                                 // [L][B][D], K-scaled
constexpr size_t OFF_REFP = OFF_REFG + (size_t)kL * kB * kD;        // K-scaled
constexpr size_t OFF_ENCQ = OFF_REFP + (size_t)kL * kB * kD;        // K*(enc@wq_p^T+bq_p)
constexpr size_t kTotalNoGx = OFF_ENCQ + (size_t)kL * kB * kD;
constexpr size_t OFF_GX   = kTotalNoGx;                             // [129*512][512]
constexpr size_t kTotalGx = OFF_GX + (size_t)129 * kB * 512;        // ~237 MB

constexpr size_t OUT_IDX_OFF = (size_t)kSteps * kB * kL;  // probs first, then idx

// ---- dynamic LDS layout for decode_main (float offsets), ~73 KB ----
constexpr int SM_REFP = 0;      // [8 it][2 slot][256 t][4] = 16384 floats, conflict-free
constexpr int SM_H    = 16384;  // [128]
constexpr int SM_C    = 16512;  // [128]
constexpr int SM_G    = 16640;  // [512] gates
constexpr int SM_RED  = 17152;  // [256] P6 q_p partials (also x-staging in non-GX tier)
constexpr int SM_QG   = 17408;  // [128]
constexpr int SM_U    = 17536;  // [128]
constexpr int SM_PG   = 17664;  // [128] glimpse probs
constexpr int SM_M    = 17792;  // [128] mask
constexpr int SM_VG   = 17920;  // [128] holds 2*v_g
constexpr int SM_VP   = 18048;  // [128] holds 2*v_p
constexpr int SM_IDX  = 18176;  // int
constexpr int SM_TOTAL= 18180;

// fast transcendentals
__device__ __forceinline__ float tanh_fast(float x) {
  return 1.0f - __fdividef(2.0f, __expf(2.0f * x) + 1.0f);
}
__device__ __forceinline__ float sig_fast(float x) {
  return __fdividef(1.0f, 1.0f + __expf(-x));
}
// raw single-instruction transcendentals (guaranteed lowering)
__device__ __forceinline__ float exp2_raw(float x) {
  float r; asm("v_exp_f32 %0, %1" : "=v"(r) : "v"(x)); return r;
}
__device__ __forceinline__ float rcp_raw(float x) {
  float r; asm("v_rcp_f32 %0, %1" : "=v"(r) : "v"(x)); return r;
}

// anchor a float4's components in VGPRs at this program point (rule #17/#18)
#define KEEP4(v) asm volatile("" : "+v"(v.x), "+v"(v.y), "+v"(v.z), "+v"(v.w))

} // namespace

// ---------- one-time: weight relayouts + fused bias ----------
extern "C" __global__ void prep_weights(
    const float* __restrict__ w_ih, const float* __restrict__ w_hh,
    const float* __restrict__ b_ih, const float* __restrict__ b_hh,
    const float* __restrict__ wq_p, const float* __restrict__ wq_g,
    const float* __restrict__ wr_p, const float* __restrict__ wr_g,
    float* __restrict__ ws) {
  const int tid = blockIdx.x * blockDim.x + threadIdx.x;
  const int nth = gridDim.x * blockDim.x;
  for (int i = tid; i < 256 * 512; i += nth) {
    const int k = i >> 9, g = i & 511;
    ws[OFF_WL + i] = (k < 128) ? w_ih[g * 128 + k] : w_hh[g * 128 + (k - 128)];
  }
  for (int i = tid; i < 512; i += nth) ws[OFF_BIAS + i] = b_ih[i] + b_hh[i];
  // WQLG: K-scaled so P3 produces q_g' = K*q_g directly
  for (int i = tid; i < 16384; i += nth) {
    const int e = i & 3, rest = i >> 2;
    const int kq = rest & 1, j = (rest >> 1) & 127, kk4 = rest >> 8;
    const int k = kq * 64 + kk4 * 4 + e;
    ws[OFF_WQLG + i] = kK * wq_g[j * 128 + k];
  }
  for (int i = tid; i < 128 * 512; i += nth) {
    const int k = i >> 9, g = i & 511;
    ws[OFF_WIHT + i] = w_ih[g * 128 + k];
  }
  for (int i = tid; i < 128 * 128; i += nth) {
    const int k = i >> 7, j = i & 127;
    ws[OFF_WQTP + i] = wq_p[j * 128 + k];
    ws[OFF_WRTG + i] = wr_g[j * 128 + k];
    ws[OFF_WRTP + i] = wr_p[j * 128 + k];
  }
}

// ---------- one-time tiled GEMM: {ref_g, ref_p, encq} = K*(enc @ W + bias) ----------
extern "C" __global__ __launch_bounds__(256) void prep_mm(
    const float* __restrict__ enc,
    const float* __restrict__ br_g, const float* __restrict__ br_p,
    const float* __restrict__ bq_p,
    float* __restrict__ ws) {
  extern __shared__ float lds[];
  float* wT = lds;          // [128 k][128 j]
  float* sx = lds + 16384;  // [64 r][128 k]
  const int t = threadIdx.x;
  const int table = blockIdx.y;
  const size_t wOff = (table == 0) ? OFF_WRTG : (table == 1) ? OFF_WRTP : OFF_WQTP;
  const size_t oOff = (table == 0) ? OFF_REFG : (table == 1) ? OFF_REFP : OFF_ENCQ;
  const float* bias = (table == 0) ? br_g : (table == 1) ? br_p : bq_p;
  for (int i = t; i < 16384; i += 256) wT[i] = ws[wOff + i];
  const size_t r0 = (size_t)blockIdx.x * 64;   // rid = l*512 + b
  for (int i = t; i < 8192; i += 256) sx[i] = enc[r0 * 128 + i];
  __syncthreads();
  const int j0 = (t & 31) * 4, rg = t >> 5;
  float4 acc[8];
  const float4 b4 = *(const float4*)(bias + j0);
  #pragma unroll
  for (int r = 0; r < 8; ++r) acc[r] = b4;
  for (int k4 = 0; k4 < 32; ++k4) {
    const float4 w0 = *(const float4*)&wT[(k4 * 4 + 0) * 128 + j0];
    const float4 w1 = *(const float4*)&wT[(k4 * 4 + 1) * 128 + j0];
    const float4 w2 = *(const float4*)&wT[(k4 * 4 + 2) * 128 + j0];
    const float4 w3 = *(const float4*)&wT[(k4 * 4 + 3) * 128 + j0];
    #pragma unroll
    for (int r = 0; r < 8; ++r) {
      const float4 xv = *(const float4*)&sx[(rg * 8 + r) * 128 + k4 * 4];
      acc[r].x += xv.x * w0.x + xv.y * w1.x + xv.z * w2.x + xv.w * w3.x;
      acc[r].y += xv.x * w0.y + xv.y * w1.y + xv.z * w2.y + xv.w * w3.y;
      acc[r].z += xv.x * w0.z + xv.y * w1.z + xv.z * w2.z + xv.w * w3.z;
      acc[r].w += xv.x * w0.w + xv.y * w1.w + xv.z * w2.w + xv.w * w3.w;
    }
  }
  #pragma unroll
  for (int r = 0; r < 8; ++r) {
    acc[r].x *= kK; acc[r].y *= kK; acc[r].z *= kK; acc[r].w *= kK;
    *(float4*)&ws[oOff + (r0 + rg * 8 + r) * 128 + j0] = acc[r];
  }
}

// ---------- one-time tiled GEMM: gx[rid][g] = x_rid . w_ih[g,:] + bias[g] ----------
extern "C" __global__ __launch_bounds__(256) void prep_gx(
    const float* __restrict__ emb, const float* __restrict__ dec0,
    float* __restrict__ ws) {
  extern __shared__ float lds[];
  float* wT = lds;          // [128 k][128 g]
  float* sx = lds + 16384;  // [64 r][128 k]
  const int t = threadIdx.x;
  const int g0 = blockIdx.y * 128;
  for (int i = t; i < 16384; i += 256) {
    wT[i] = ws[OFF_WIHT + (size_t)(i >> 7) * 512 + g0 + (i & 127)];
  }
  const size_t r0 = (size_t)blockIdx.x * 64;
  for (int i = t; i < 8192; i += 256) {
    const size_t rid = r0 + (i >> 7);
    const int c = i & 127;
    sx[i] = (rid < 65536) ? emb[rid * 128 + c] : dec0[(rid - 65536) * 128 + c];
  }
  __syncthreads();
  const int j0 = (t & 31) * 4, rg = t >> 5;
  float4 acc[8];
  const float4 b4 = *(const float4*)(ws + OFF_BIAS + g0 + j0);
  #pragma unroll
  for (int r = 0; r < 8; ++r) acc[r] = b4;
  for (int k4 = 0; k4 < 32; ++k4) {
    const float4 w0 = *(const float4*)&wT[(k4 * 4 + 0) * 128 + j0];
    const float4 w1 = *(const float4*)&wT[(k4 * 4 + 1) * 128 + j0];
    const float4 w2 = *(const float4*)&wT[(k4 * 4 + 2) * 128 + j0];
    const float4 w3 = *(const float4*)&wT[(k4 * 4 + 3) * 128 + j0];
    #pragma unroll
    for (int r = 0; r < 8; ++r) {
      const float4 xv = *(const float4*)&sx[(rg * 8 + r) * 128 + k4 * 4];
      acc[r].x += xv.x * w0.x + xv.y * w1.x + xv.z * w2.x + xv.w * w3.x;
      acc[r].y += xv.x * w0.y + xv.y * w1.y + xv.z * w2.y + xv.w * w3.y;
      acc[r].z += xv.x * w0.z + xv.y * w1.z + xv.z * w2.z + xv.w * w3.z;
      acc[r].w += xv.x * w0.w + xv.y * w1.w + xv.z * w2.w + xv.w * w3.w;
    }
  }
  #pragma unroll
  for (int r = 0; r < 8; ++r) {
    *(float4*)&ws[OFF_GX + (r0 + rg * 8 + r) * 512 + g0 + j0] = acc[r];
  }
}

// ---------- persistent decode: one block per batch element, 256 threads, 2/CU ----------
// r16 final: refg step-top prefetch (32 regs, fits); ENCQ streamed in P6
// (r15/r17/r18 proved any larger prefetch spills); rcp/exp2 score form.
template <bool GX>
__global__ __launch_bounds__(256, 2) void decode_main(
    const float* __restrict__ dec0, const float* __restrict__ emb,
    const float* __restrict__ h0,   const float* __restrict__ c0,
    const float* __restrict__ bq_g, const float* __restrict__ v_p,
    const float* __restrict__ v_g,
    const float* __restrict__ ws, float* __restrict__ out) {
  extern __shared__ float sm[];
  int* s_idx = (int*)(sm + SM_IDX);

  const int t = threadIdx.x;
  const int b = blockIdx.x;
  const int wv = t >> 6, lane = t & 63;
  const int sub = lane & 15, rr = lane >> 4;
  const int j2 = t >> 1, kq = t & 1;     // P3 mapping
  const int lh = t >> 7, dd = t & 127;   // P6 mapping

  // ---- startup: ref_p (K-scaled) -> LDS, conflict-free split-float4 slots ----
  #pragma unroll
  for (int it = 0; it < 8; ++it) {
    const int l = it * 16 + wv * 4 + rr;
    const float* src = ws + OFF_REFP + ((size_t)l * kB + b) * kD + sub * 8;
    *(float4*)&sm[SM_REFP + (it * 512 + t) * 4]       = *(const float4*)src;
    *(float4*)&sm[SM_REFP + (it * 512 + 256 + t) * 4] = *(const float4*)(src + 4);
  }
  if (t < 128) {
    sm[SM_H + t]  = h0[b * 128 + t];
    sm[SM_C + t]  = c0[b * 128 + t];
    sm[SM_M + t]  = (t < 2) ? 1.f : 0.f;   // indices 0,1 pre-visited
    sm[SM_VG + t] = 2.0f * v_g[t];         // 2v tables for the rcp form
    sm[SM_VP + t] = 2.0f * v_p[t];
  }
  if (t == 0) *s_idx = 128;   // sentinel: dec0 row
  const float bqg = kK * bq_g[j2];
  const float bias0 = ws[OFF_BIAS + 2 * t];
  const float bias1 = ws[OFF_BIAS + 2 * t + 1];
  __syncthreads();

  // vsum scalars (Σv = 0.5 * Σ(2v); broadcast LDS reads)
  float vgsum = 0.f, vpsum = 0.f;
  #pragma unroll 8
  for (int i = 0; i < 128; i += 4) {
    const float4 a = *(const float4*)&sm[SM_VG + i];
    const float4 p = *(const float4*)&sm[SM_VP + i];
    vgsum += a.x + a.y + a.z + a.w;
    vpsum += p.x + p.y + p.z + p.w;
  }
  vgsum *= 0.5f; vpsum *= 0.5f;

  const float* WL  = ws + OFF_WL;
  const float* WHH = WL + 128 * 512;
  const float* WQG = ws + OFF_WQLG + 4 * t;
  const float* REFG = ws + OFF_REFG;
  const float* ENCQ = ws + OFF_ENCQ;
  const float* GXT  = ws + OFF_GX;

  // per-it refg source pointers (step-invariant addresses)
  const float* rgp0 = REFG + ((size_t)( 0 + wv * 4 + rr) * kB + b) * kD + sub * 8;
  const float* rgp1 = REFG + ((size_t)(16 + wv * 4 + rr) * kB + b) * kD + sub * 8;
  const float* rgp2 = REFG + ((size_t)(32 + wv * 4 + rr) * kB + b) * kD + sub * 8;
  const float* rgp3 = REFG + ((size_t)(48 + wv * 4 + rr) * kB + b) * kD + sub * 8;
  const float* rgp4 = REFG + ((size_t)(64 + wv * 4 + rr) * kB + b) * kD + sub * 8;
  const float* rgp5 = REFG + ((size_t)(80 + wv * 4 + rr) * kB + b) * kD + sub * 8;
  const float* rgp6 = REFG + ((size_t)(96 + wv * 4 + rr) * kB + b) * kD + sub * 8;
  const float* rgp7 = REFG + ((size_t)(112 + wv * 4 + rr) * kB + b) * kD + sub * 8;

  for (int step = 0; step < kSteps; ++step) {
    // ---- T14: issue refg loads NOW; consumed in P4 (hidden under P1-P3) ----
    float4 ga0 = *(const float4*)rgp0, gb0 = *(const float4*)(rgp0 + 4);
    float4 ga1 = *(const float4*)rgp1, gb1 = *(const float4*)(rgp1 + 4);
    float4 ga2 = *(const float4*)rgp2, gb2 = *(const float4*)(rgp2 + 4);
    float4 ga3 = *(const float4*)rgp3, gb3 = *(const float4*)(rgp3 + 4);
    float4 ga4 = *(const float4*)rgp4, gb4 = *(const float4*)(rgp4 + 4);
    float4 ga5 = *(const float4*)rgp5, gb5 = *(const float4*)(rgp5 + 4);
    float4 ga6 = *(const float4*)rgp6, gb6 = *(const float4*)(rgp6 + 4);
    float4 ga7 = *(const float4*)rgp7, gb7 = *(const float4*)(rgp7 + 4);
    KEEP4(ga0); KEEP4(gb0); KEEP4(ga1); KEEP4(gb1);
    KEEP4(ga2); KEEP4(gb2); KEEP4(ga3); KEEP4(gb3);
    KEEP4(ga4); KEEP4(gb4); KEEP4(ga5); KEEP4(gb5);
    KEEP4(ga6); KEEP4(gb6); KEEP4(ga7); KEEP4(gb7);
    // ---- P1: gates(2t,2t+1) = (gx or W_ih.x) + W_hh.h ----
    {
      float a0, a1;
      const int row = *s_idx;
      if constexpr (GX) {
        const float2 gx2 = *(const float2*)(GXT + ((size_t)row * kB + b) * 512 + 2 * t);
        a0 = gx2.x; a1 = gx2.y;
      } else {
        if (t < 128) {
          const float* xs = (row == 128) ? dec0 + (size_t)b * 128
                                         : emb + ((size_t)row * kB + b) * kD;
          sm[SM_RED + t] = xs[t];
        }
        __syncthreads();
        a0 = bias0; a1 = bias1;
        const float* wp = WL + 2 * t;
        #pragma unroll 8
        for (int k4 = 0; k4 < 32; ++k4) {
          const float4 x4 = *(const float4*)&sm[SM_RED + k4 * 4];
          const float2 w0 = *(const float2*)(wp + (size_t)(k4 * 4 + 0) * 512);
          const float2 w1 = *(const float2*)(wp + (size_t)(k4 * 4 + 1) * 512);
          const float2 w2 = *(const float2*)(wp + (size_t)(k4 * 4 + 2) * 512);
          const float2 w3 = *(const float2*)(wp + (size_t)(k4 * 4 + 3) * 512);
          a0 += x4.x * w0.x + x4.y * w1.x + x4.z * w2.x + x4.w * w3.x;
          a1 += x4.x * w0.y + x4.y * w1.y + x4.z * w2.y + x4.w * w3.y;
        }
      }
      const float* wp = WHH + 2 * t;
      #pragma unroll 8
      for (int k4 = 0; k4 < 32; ++k4) {
        const float4 h4 = *(const float4*)&sm[SM_H + k4 * 4];
        const float2 w0 = *(const float2*)(wp + (size_t)(k4 * 4 + 0) * 512);
        const float2 w1 = *(const float2*)(wp + (size_t)(k4 * 4 + 1) * 512);
        const float2 w2 = *(const float2*)(wp + (size_t)(k4 * 4 + 2) * 512);
        const float2 w3 = *(const float2*)(wp + (size_t)(k4 * 4 + 3) * 512);
        a0 += h4.x * w0.x + h4.y * w1.x + h4.z * w2.x + h4.w * w3.x;
        a1 += h4.x * w0.y + h4.y * w1.y + h4.z * w2.y + h4.w * w3.y;
      }
      *(float2*)&sm[SM_G + 2 * t] = make_float2(a0, a1);
    }
    __syncthreads();  // B1
    // ---- P2: LSTM cell (t<128); mask update (use_prev only) ----
    if (t < 128) {
      const float gi = sm[SM_G + t];
      const float gf = sm[SM_G + 128 + t];
      const float gg = sm[SM_G + 256 + t];
      const float go = sm[SM_G + 384 + t];
      const float cc = sig_fast(gf) * sm[SM_C + t] + sig_fast(gi) * tanh_fast(gg);
      sm[SM_C + t] = cc;
      sm[SM_H + t] = sig_fast(go) * tanh_fast(cc);
    } else if (t == 128 && step > 0) {
      sm[SM_M + *s_idx] = 1.f;
    }
    __syncthreads();  // B2
    // ---- P3: q_g'[j] = K*(h . wq_g[j] + bq_g) (K folded into WQLG/bqg) ----
    {
      float acc = 0.f;
      #pragma unroll 4
      for (int kk4 = 0; kk4 < 16; ++kk4) {
        const float4 w  = *(const float4*)(WQG + (size_t)kk4 * 1024);
        const float4 h4 = *(const float4*)&sm[SM_H + kq * 64 + kk4 * 4];
        acc += h4.x * w.x + h4.y * w.y + h4.z * w.z + h4.w * w.w;
      }
      acc += __shfl_xor(acc, 1);
      if (!kq) sm[SM_QG + j2] = acc + bqg;
    }
    __syncthreads();  // B3
    // ---- P4: glimpse scores via rcp form: u = vgsum - sum 2v*rcp(exp2(r'+q')+1) ----
    {
      const float4 qa = *(const float4*)&sm[SM_QG + sub * 8];
      const float4 qb = *(const float4*)&sm[SM_QG + sub * 8 + 4];
      const float4 va = *(const float4*)&sm[SM_VG + sub * 8];
      const float4 vb = *(const float4*)&sm[SM_VG + sub * 8 + 4];
      #define P4_ROW(IT, RA, RB)                                            \
      {                                                                     \
        const int l = IT * 16 + wv * 4 + rr;                                \
        float s2;                                                           \
        s2  = va.x * rcp_raw(exp2_raw(RA.x + qa.x) + 1.0f);                 \
        s2 += va.y * rcp_raw(exp2_raw(RA.y + qa.y) + 1.0f);                 \
        s2 += va.z * rcp_raw(exp2_raw(RA.z + qa.z) + 1.0f);                 \
        s2 += va.w * rcp_raw(exp2_raw(RA.w + qa.w) + 1.0f);                 \
        s2 += vb.x * rcp_raw(exp2_raw(RB.x + qb.x) + 1.0f);                 \
        s2 += vb.y * rcp_raw(exp2_raw(RB.y + qb.y) + 1.0f);                 \
        s2 += vb.z * rcp_raw(exp2_raw(RB.z + qb.z) + 1.0f);                 \
        s2 += vb.w * rcp_raw(exp2_raw(RB.w + qb.w) + 1.0f);                 \
        s2 += __shfl_xor(s2, 1); s2 += __shfl_xor(s2, 2);                   \
        s2 += __shfl_xor(s2, 4); s2 += __shfl_xor(s2, 8);                   \
        if (sub == 0) {                                                     \
          float u = vgsum - s2;                                             \
          if (step > 0 && sm[SM_M + l] != 0.f) u = -INFINITY;               \
          sm[SM_U + l] = u;                                                 \
        }                                                                   \
      }
      P4_ROW(0, ga0, gb0) P4_ROW(1, ga1, gb1)
      P4_ROW(2, ga2, gb2) P4_ROW(3, ga3, gb3)
      P4_ROW(4, ga4, gb4) P4_ROW(5, ga5, gb5)
      P4_ROW(6, ga6, gb6) P4_ROW(7, ga7, gb7)
      #undef P4_ROW
    }
    __syncthreads();  // B4
    // ---- P5: glimpse softmax (wave 0) -> PG ----
    if (t < 64) {
      const float v0 = sm[SM_U + t], v1 = sm[SM_U + 64 + t];
      float m = fmaxf(v0, v1);
      #pragma unroll
      for (int off = 1; off < 64; off <<= 1) m = fmaxf(m, __shfl_xor(m, off, 64));
      const float e0 = __expf(v0 - m), e1 = __expf(v1 - m);
      float ssum = e0 + e1;
      #pragma unroll
      for (int off = 1; off < 64; off <<= 1) ssum += __shfl_xor(ssum, off, 64);
      const float inv = __fdividef(1.0f, ssum);
      sm[SM_PG + t]      = e0 * inv;
      sm[SM_PG + 64 + t] = e1 * inv;
    }
    __syncthreads();  // B5
    // ---- P6: q_p' partials directly from encq (K-scaled; p sums to 1) ----
    {
      float acc = 0.f;
      #pragma unroll 8
      for (int ll = 0; ll < 64; ++ll) {
        const int l = lh * 64 + ll;
        acc += sm[SM_PG + l] * ENCQ[((size_t)l * kB + b) * kD + dd];
      }
      sm[SM_RED + t] = acc;   // RED[lh*128 + dd]
    }
    __syncthreads();  // B6
    // ---- P8: fold q_p'; pointer scores via rcp form; 10*tanh clip; mask ----
    {
      const float4 r0a = *(const float4*)&sm[SM_RED + sub * 8];
      const float4 r0b = *(const float4*)&sm[SM_RED + sub * 8 + 4];
      const float4 r1a = *(const float4*)&sm[SM_RED + 128 + sub * 8];
      const float4 r1b = *(const float4*)&sm[SM_RED + 128 + sub * 8 + 4];
      const float4 qa = make_float4(r0a.x + r1a.x, r0a.y + r1a.y,
                                    r0a.z + r1a.z, r0a.w + r1a.w);
      const float4 qb = make_float4(r0b.x + r1b.x, r0b.y + r1b.y,
                                    r0b.z + r1b.z, r0b.w + r1b.w);
      const float4 va = *(const float4*)&sm[SM_VP + sub * 8];
      const float4 vb = *(const float4*)&sm[SM_VP + sub * 8 + 4];
      #pragma unroll
      for (int it = 0; it < 8; ++it) {
        const int l = it * 16 + wv * 4 + rr;
        const float4 ra = *(const float4*)&sm[SM_REFP + (it * 512 + t) * 4];
        const float4 rb = *(const float4*)&sm[SM_REFP + (it * 512 + 256 + t) * 4];
        float s2;
        s2  = va.x * rcp_raw(exp2_raw(ra.x + qa.x) + 1.0f);
        s2 += va.y * rcp_raw(exp2_raw(ra.y + qa.y) + 1.0f);
        s2 += va.z * rcp_raw(exp2_raw(ra.z + qa.z) + 1.0f);
        s2 += va.w * rcp_raw(exp2_raw(ra.w + qa.w) + 1.0f);
        s2 += vb.x * rcp_raw(exp2_raw(rb.x + qb.x) + 1.0f);
        s2 += vb.y * rcp_raw(exp2_raw(rb.y + qb.y) + 1.0f);
        s2 += vb.z * rcp_raw(exp2_raw(rb.z + qb.z) + 1.0f);
        s2 += vb.w * rcp_raw(exp2_raw(rb.w + qb.w) + 1.0f);
        s2 += __shfl_xor(s2, 1); s2 += __shfl_xor(s2, 2);
        s2 += __shfl_xor(s2, 4); s2 += __shfl_xor(s2, 8);
        if (sub == 0) {
          float uu = 10.f * tanh_fast(vpsum - s2);
          if (step > 0 && sm[SM_M + l] != 0.f) uu = -INFINITY;
          sm[SM_U + l] = uu;
        }
      }
    }
    __syncthreads();  // B7
    // ---- P9: pointer softmax + argmax; write probs + idx directly ----
    if (t < 64) {
      const float v0 = sm[SM_U + t], v1 = sm[SM_U + 64 + t];
      float m = fmaxf(v0, v1);
      #pragma unroll
      for (int off = 1; off < 64; off <<= 1) m = fmaxf(m, __shfl_xor(m, off, 64));
      const float e0 = __expf(v0 - m), e1 = __expf(v1 - m);
      float ssum = e0 + e1;
      #pragma unroll
      for (int off = 1; off < 64; off <<= 1) ssum += __shfl_xor(ssum, off, 64);
      const float inv = __fdividef(1.0f, ssum);
      float* orow = out + ((size_t)step * kB + b) * kL;
      orow[t]      = e0 * inv;
      orow[64 + t] = e1 * inv;
      float av; int ai;
      if (v0 >= v1) { av = v0; ai = t; } else { av = v1; ai = t + 64; }
      #pragma unroll
      for (int off = 1; off < 64; off <<= 1) {
        const float ov = __shfl_xor(av, off, 64);
        const int   oi = __shfl_xor(ai, off, 64);
        if (ov > av || (ov == av && oi < ai)) { av = ov; ai = oi; }
      }
      if (t == 0) {
        *s_idx = ai;
        out[OUT_IDX_OFF + (size_t)step * kB + b] = (float)ai;
      }
    }
    __syncthreads();  // B8
  }
}

extern "C" void kernel_launch(void* const* d_in, const int* in_sizes, int n_in,
                              void* d_out, int out_size, void* d_ws, size_t ws_size,
                              hipStream_t stream) {
  (void)in_sizes; (void)n_in; (void)out_size;
  const float* dec0 = (const float*)d_in[0];
  const float* emb  = (const float*)d_in[1];
  const float* h0   = (const float*)d_in[2];
  const float* c0   = (const float*)d_in[3];
  const float* enc  = (const float*)d_in[4];
  const float* w_ih = (const float*)d_in[5];
  const float* w_hh = (const float*)d_in[6];
  const float* b_ih = (const float*)d_in[7];
  const float* b_hh = (const float*)d_in[8];
  const float* wq_p = (const float*)d_in[9];
  const float* bq_p = (const float*)d_in[10];
  const float* wr_p = (const float*)d_in[11];
  const float* br_p = (const float*)d_in[12];
  const float* v_p  = (const float*)d_in[13];
  const float* wq_g = (const float*)d_in[14];
  const float* bq_g = (const float*)d_in[15];
  const float* wr_g = (const float*)d_in[16];
  const float* br_g = (const float*)d_in[17];
  const float* v_g  = (const float*)d_in[18];
  float* ws  = (float*)d_ws;
  float* out = (float*)d_out;

  const bool gx_ok = ws_size >= kTotalGx * 4;   // ~237 MB with the gx table

  prep_weights<<<dim3(64), dim3(256), 0, stream>>>(
      w_ih, w_hh, b_ih, b_hh, wq_p, wq_g, wr_p, wr_g, ws);
  prep_mm<<<dim3(1024, 3), dim3(256), 24576 * 4, stream>>>(
      enc, br_g, br_p, bq_p, ws);
  if (gx_ok) {
    prep_gx<<<dim3(1032, 4), dim3(256), 24576 * 4, stream>>>(emb, dec0, ws);
    decode_main<true><<<dim3(512), dim3(256), SM_TOTAL * 4, stream>>>(
        dec0, emb, h0, c0, bq_g, v_p, v_g, ws, out);
  } else {
    decode_main<false><<<dim3(512), dim3(256), SM_TOTAL * 4, stream>>>(
        dec0, emb, h0, c0, bq_g, v_p, v_g, ws, out);
  }
}